// Round 17
// baseline (44.649 us; speedup 1.0000x reference)
//
#include <hip/hip_runtime.h>
#include <cstddef>
#include <cstdint>

// KPNextBlock: M=N=50000, H=32, C=128, K=15, GROUPS=8, CPG=16 -> K*CPG=240,
// RADIUS=1.2, SIGMA=0.9.
namespace {
constexpr int H_N  = 32;
constexpr int C_F  = 128;
constexpr int K_P  = 15;
constexpr int MODC = 240;
constexpr int QB   = 64;                  // queries per block
constexpr int TILE_SZ = QB * MODC * 2;    // 30720: x/h swz [0,16K), then mod
}

typedef __attribute__((ext_vector_type(8))) short short8v;
typedef __attribute__((ext_vector_type(4))) float f32x4;

__device__ __forceinline__ unsigned short bf16_hi(float f) {
    unsigned u = __builtin_bit_cast(unsigned, f);
    unsigned r = (u + 0x7FFFu + ((u >> 16) & 1u)) >> 16;
    return (unsigned short)r;
}
__device__ __forceinline__ float bf16_f(unsigned short h) {
    unsigned u = ((unsigned)h) << 16;
    return __builtin_bit_cast(float, u);
}

// ---------------------------------------------------------------------------
// Pre-pass: transpose weights to bf16 [col][k] so MFMA B-fragments are
// 16B-contiguous per lane.
// ---------------------------------------------------------------------------
__global__ __launch_bounds__(256)
void split_w_kernel(const float* __restrict__ w1, const float* __restrict__ w2,
                    unsigned short* __restrict__ w1t, unsigned short* __restrict__ w2t)
{
    const int i = blockIdx.x * 256 + threadIdx.x;
    if (i < C_F * C_F) {
        const int c = i >> 7, j = i & 127;          // w1[c][j]
        w1t[j * C_F + c] = bf16_hi(w1[i]);
    }
    const int i2 = i - C_F * C_F;
    if (i2 >= 0 && i2 < C_F * MODC) {
        const int c = i2 / MODC, j = i2 - c * MODC; // w2[c][j]
        w2t[j * C_F + c] = bf16_hi(w2[i2]);
    }
}

// ---------------------------------------------------------------------------
// SINGLE fused kernel, per 64-query block (8 waves, 512 threads):
//   1) geometry, software-pipelined (4 passes, half-wave per query):
//      inactive queries (~70%) -> out=0 directly; active -> records in LDS
//      (LDS atomic slot; NO global atomics, NO global record round-trip).
//   2) MFMA MLP on the block's cnt (<=64) active rows: x gathered via LDS
//      qidx_l -> GEMM1 (h->LDS) -> GEMM2 -> sigmoid -> mod->LDS (reused tile).
//   3) gather tail: records + mod from LDS, out written per active query.
// Eliminates rounds-14..16's 3-launch chain + 13MB pk/gfl/qidx round-trip +
// counter dependency + 547 dead blocks. Blocks overlap phases via TLP.
// ---------------------------------------------------------------------------
__global__ __launch_bounds__(512, 2)
void fused_kernel(const float* __restrict__ q_pts,
                  const float* __restrict__ s_pts,
                  const float* __restrict__ s_feats,
                  const int* __restrict__ nbi,
                  const float* __restrict__ da_scale,
                  const float* __restrict__ weights,
                  const float* __restrict__ kp,
                  const unsigned short* __restrict__ w1t,
                  const unsigned short* __restrict__ w2t,
                  const float* __restrict__ b1,
                  float* __restrict__ out,
                  int M)
{
    __shared__ int      qidx_l[QB];
    __shared__ unsigned pk_l [QB * H_N];
    __shared__ float    gfl_l[QB * H_N];
    __shared__ int      cnt_l;
    __shared__ __align__(16) unsigned char tile[TILE_SZ];

    const int t    = threadIdx.x;
    const int wave = t >> 6, lane = t & 63;
    const int hl   = lane & 31;
    const int half = lane >> 5;
    const int q0   = blockIdx.x * QB;

    if (t == 0) cnt_l = 0;
    __syncthreads();

    // ---- prefetch weight fragments into registers (independent of geometry) ----
    const int g  = lane >> 4;      // k-block
    const int ln = lane & 15;
    short8v w1f[4];
    #pragma unroll
    for (int ks = 0; ks < 4; ++ks)
        w1f[ks] = *reinterpret_cast<const short8v*>(
            w1t + (size_t)(wave * 16 + ln) * C_F + ks * 32 + g * 8);
    short8v w2f[4][2];
    #pragma unroll
    for (int ks = 0; ks < 4; ++ks) {
        #pragma unroll
        for (int cs = 0; cs < 2; ++cs) {
            const int ctile = wave + 8 * cs;
            const int colc = (ctile < K_P ? ctile : 0) * 16 + ln;   // clamp: safe load
            w2f[ks][cs] = *reinterpret_cast<const short8v*>(
                w2t + (size_t)colc * C_F + ks * 32 + g * 8);
        }
    }

    // ================= 1) geometry, pipelined over 4 passes =================
    {
        float qx[4], qy[4], qz[4], das[4];
        int   idx[4];
        bool  valid[4];
        #pragma unroll
        for (int p = 0; p < 4; ++p) {
            const int ql = q0 + p * 16 + wave * 2 + half;
            valid[p] = ql < M;
            const int qc = valid[p] ? ql : 0;
            qx[p]  = q_pts[qc * 3 + 0];
            qy[p]  = q_pts[qc * 3 + 1];
            qz[p]  = q_pts[qc * 3 + 2];
            das[p] = da_scale[qc];
            idx[p] = nbi[(size_t)qc * H_N + hl];
        }
        float sx[4], sy[4], sz[4];
        #pragma unroll
        for (int p = 0; p < 4; ++p) {
            sx[p] = s_pts[idx[p] * 3 + 0];
            sy[p] = s_pts[idx[p] * 3 + 1];
            sz[p] = s_pts[idx[p] * 3 + 2];
        }

        #pragma unroll
        for (int p = 0; p < 4; ++p) {
            const int ql = q0 + p * 16 + wave * 2 + half;
            int   nn = 0;
            float fl = 0.f;
            if (valid[p]) {
                // plain fp32 (no fma contraction): match numpy rounding at argmin ties
                const float dx = __fsub_rn(sx[p], qx[p]);
                const float dy = __fsub_rn(sy[p], qy[p]);
                const float dz = __fsub_rn(sz[p], qz[p]);
                const float dd = __fadd_rn(__fadd_rn(__fmul_rn(dx, dx), __fmul_rn(dy, dy)),
                                           __fmul_rn(dz, dz));
                // |kp| < 1.2 strictly => |d| >= 0.9+1.2*da implies infl == 0 exactly.
                const float reach = 0.9f + 1.2f * das[p];
                if (dd < reach * reach) {
                    float best = 3.4e38f; int bi = 0;
                    #pragma unroll
                    for (int k = 0; k < K_P; ++k) {
                        const float ex = __fsub_rn(dx, __fmul_rn(kp[k * 3 + 0], das[p]));
                        const float ey = __fsub_rn(dy, __fmul_rn(kp[k * 3 + 1], das[p]));
                        const float ez = __fsub_rn(dz, __fmul_rn(kp[k * 3 + 2], das[p]));
                        const float d2 = __fadd_rn(__fadd_rn(__fmul_rn(ex, ex), __fmul_rn(ey, ey)),
                                                   __fmul_rn(ez, ez));
                        if (d2 < best) { best = d2; bi = k; }
                    }
                    const float f = 1.f - sqrtf(best) / 0.9f;
                    fl = fmaxf(f, 0.f);
                    nn = bi;
                }
            }

            const unsigned long long mask = __ballot(fl > 0.f);
            const unsigned long long mymask = half ? (mask & 0xFFFFFFFF00000000ull)
                                                   : (mask & 0x00000000FFFFFFFFull);
            if (valid[p] && mymask == 0ull) {
                // inactive: output row is exactly zero (32 lanes x float4)
                *reinterpret_cast<float4*>(out + (size_t)ql * C_F + hl * 4) =
                    make_float4(0.f, 0.f, 0.f, 0.f);
            } else if (valid[p]) {
                int slot = 0;
                if (hl == 0) slot = atomicAdd(&cnt_l, 1);    // LDS atomic: cheap
                slot = __shfl(slot, half * 32);
                if (hl == 0) qidx_l[slot] = ql;
                pk_l [slot * H_N + hl] = (unsigned)idx[p] | ((unsigned)nn << 20);
                gfl_l[slot * H_N + hl] = fl;
            }
        }
    }
    __syncthreads();

    const int cnt = cnt_l;
    if (cnt == 0) return;

    // ================= 2) MLP on the block's active rows =================
    // ---- stage x (gathered rows): fp32 -> bf16, swizzled LDS [row][k] ----
    {
        const int row = t >> 3;          // 0..63
        const int k0  = (t & 7) << 4;    // 0,16,...,112
        const int src_m = (row < cnt) ? qidx_l[row] : 0;
        const float4* src = reinterpret_cast<const float4*>(
            s_feats + (size_t)src_m * C_F + k0);
        #pragma unroll
        for (int s = 0; s < 2; ++s) {
            float v[8];
            if (row < cnt) {
                const float4 a = src[s * 2 + 0];
                const float4 b = src[s * 2 + 1];
                v[0] = a.x; v[1] = a.y; v[2] = a.z; v[3] = a.w;
                v[4] = b.x; v[5] = b.y; v[6] = b.z; v[7] = b.w;
            } else {
                #pragma unroll
                for (int e = 0; e < 8; ++e) v[e] = 0.f;
            }
            short8v hv;
            #pragma unroll
            for (int e = 0; e < 8; ++e) hv[e] = (short)bf16_hi(v[e]);
            const unsigned addr = (unsigned)((row * 256 + (k0 + s * 8) * 2) ^ ((row & 7) << 4));
            *reinterpret_cast<short8v*>(tile + addr) = hv;
        }
    }
    __syncthreads();

    // ---- GEMM1: h = leaky_relu(x @ w1 + b1); wave owns col-tile `wave` ----
    {
        const int col = wave * 16 + ln;
        f32x4 acc[4];
        {
            const float b = b1[col];
            #pragma unroll
            for (int rt = 0; rt < 4; ++rt) acc[rt] = f32x4{b, b, b, b};
        }
        #pragma unroll
        for (int ks = 0; ks < 4; ++ks) {
            short8v a[4];
            #pragma unroll
            for (int rt = 0; rt < 4; ++rt) {
                const int row = rt * 16 + ln;
                const unsigned addr = (unsigned)((row * 256 + (ks * 32 + g * 8) * 2) ^ ((row & 7) << 4));
                a[rt] = *reinterpret_cast<const short8v*>(tile + addr);
            }
            #pragma unroll
            for (int rt = 0; rt < 4; ++rt)
                acc[rt] = __builtin_amdgcn_mfma_f32_16x16x32_bf16(a[rt], w1f[ks], acc[rt], 0, 0, 0);
        }
        __syncthreads();   // all waves done reading x before h overwrites it

        // leaky_relu + writeback (C/D: col=ln, row=g*4+r)
        #pragma unroll
        for (int rt = 0; rt < 4; ++rt) {
            #pragma unroll
            for (int r = 0; r < 4; ++r) {
                float v = acc[rt][r];
                v = v > 0.f ? v : 0.1f * v;
                const int row = rt * 16 + g * 4 + r;
                const unsigned addr = (unsigned)((row * 256 + col * 2) ^ ((row & 7) << 4));
                *reinterpret_cast<unsigned short*>(tile + addr) = bf16_hi(v);
            }
        }
    }
    __syncthreads();

    // ---- GEMM2: mod = sigmoid(h @ w2) in registers; wave owns {w, w+8} ----
    f32x4 acc2[4][2];
    #pragma unroll
    for (int rt = 0; rt < 4; ++rt)
        #pragma unroll
        for (int cs = 0; cs < 2; ++cs) acc2[rt][cs] = f32x4{0.f, 0.f, 0.f, 0.f};

    #pragma unroll
    for (int ks = 0; ks < 4; ++ks) {
        short8v a[4];
        #pragma unroll
        for (int rt = 0; rt < 4; ++rt) {
            const int row = rt * 16 + ln;
            const unsigned addr = (unsigned)((row * 256 + (ks * 32 + g * 8) * 2) ^ ((row & 7) << 4));
            a[rt] = *reinterpret_cast<const short8v*>(tile + addr);
        }
        #pragma unroll
        for (int cs = 0; cs < 2; ++cs) {
            const int ctile = wave + 8 * cs;    // wave-uniform guard, static acc idx
            if (ctile < K_P) {
                #pragma unroll
                for (int rt = 0; rt < 4; ++rt)
                    acc2[rt][cs] = __builtin_amdgcn_mfma_f32_16x16x32_bf16(a[rt], w2f[ks][cs], acc2[rt][cs], 0, 0, 0);
            }
        }
    }
    #pragma unroll
    for (int rt = 0; rt < 4; ++rt)
        #pragma unroll
        for (int cs = 0; cs < 2; ++cs)
            #pragma unroll
            for (int r = 0; r < 4; ++r)
                acc2[rt][cs][r] = 1.f / (1.f + __expf(-acc2[rt][cs][r]));

    __syncthreads();   // h reads complete -> mod may overwrite the tile

    // ---- mod -> LDS (linear bf16 [64][240]) ----
    #pragma unroll
    for (int rt = 0; rt < 4; ++rt) {
        #pragma unroll
        for (int cs = 0; cs < 2; ++cs) {
            const int ctile = wave + 8 * cs;
            if (ctile < K_P) {
                const int col = ctile * 16 + ln;
                #pragma unroll
                for (int r = 0; r < 4; ++r) {
                    const int row = rt * 16 + g * 4 + r;
                    *reinterpret_cast<unsigned short*>(
                        tile + row * (MODC * 2) + col * 2) = bf16_hi(acc2[rt][cs][r]);
                }
            }
        }
    }
    __syncthreads();

    // ================= 3) gather tail (records + mod from LDS) =================
    const int c0 = hl << 2;          // 4 channels per lane
    for (int i = 0; i < 4; ++i) {
        const int pos = i * 16 + wave * 2 + half;
        const bool valid = pos < cnt;

        int   idx = 0, nn = 0;
        float fl  = 0.f;
        if (valid) {
            const unsigned r = pk_l[pos * H_N + hl];
            idx = (int)(r & 0xFFFFFu);
            nn  = (int)(r >> 20);
            fl  = gfl_l[pos * H_N + hl];
        }

        const unsigned long long mask = __ballot(fl > 0.f);
        unsigned long long mymask = half ? (mask & 0xFFFFFFFF00000000ull)
                                         : (mask & 0x00000000FFFFFFFFull);
        float4 acc = {0.f, 0.f, 0.f, 0.f};
        while (mymask) {
            const int hb = __builtin_ctzll(mymask);   // absolute lane (correct half)
            mymask &= mymask - 1;
            const int   ih = __shfl(idx, hb);
            const int   nh = __shfl(nn, hb);
            const float fh = __shfl(fl, hb);
            const float4 fv = *reinterpret_cast<const float4*>(s_feats + (size_t)ih * C_F + c0);
            const float4 wv = *reinterpret_cast<const float4*>(weights + nh * C_F + c0);
            const float  mv = bf16_f(*reinterpret_cast<const unsigned short*>(
                tile + pos * (MODC * 2) + (nh * 16 + (hl >> 1)) * 2));
            const float  s  = fh * mv;
            acc.x = fmaf(fv.x * wv.x, s, acc.x);
            acc.y = fmaf(fv.y * wv.y, s, acc.y);
            acc.z = fmaf(fv.z * wv.z, s, acc.z);
            acc.w = fmaf(fv.w * wv.w, s, acc.w);
        }
        if (valid)
            *reinterpret_cast<float4*>(out + (size_t)qidx_l[pos] * C_F + c0) = acc;
    }
}

// ---------------------------------------------------------------------------
extern "C" void kernel_launch(void* const* d_in, const int* in_sizes, int n_in,
                              void* d_out, int out_size, void* d_ws, size_t ws_size,
                              hipStream_t stream)
{
    const float* q_pts  = (const float*)d_in[0];
    const float* s_pts  = (const float*)d_in[1];
    const float* s_feat = (const float*)d_in[2];
    const int*   nbi    = (const int*)d_in[3];
    const float* da     = (const float*)d_in[4];
    const float* wts    = (const float*)d_in[5];
    const float* w1     = (const float*)d_in[6];
    const float* b1     = (const float*)d_in[7];
    const float* w2     = (const float*)d_in[8];
    const float* kp     = (const float*)d_in[9];
    float* out = (float*)d_out;

    const int M = in_sizes[4];   // da_scale has M elements

    // workspace: only the transposed bf16 weights (92KB)
    unsigned short* w1t = (unsigned short*)d_ws;
    unsigned short* w2t = w1t + C_F * C_F;

    const int nsplit = (C_F * C_F + C_F * MODC + 255) / 256;
    split_w_kernel<<<dim3(nsplit), 256, 0, stream>>>(w1, w2, w1t, w2t);

    fused_kernel<<<dim3((M + QB - 1) / QB), 512, 0, stream>>>(
        q_pts, s_pts, s_feat, nbi, da, wts, kp, w1t, w2t, b1, out, M);
}

// Round 18
// 42.440 us; speedup vs baseline: 1.0521x; 1.0521x over previous
//
#include <hip/hip_runtime.h>
#include <cstddef>
#include <cstdint>

// KPNextBlock: M=N=50000, H=32, C=128, K=15, GROUPS=8, CPG=16 -> K*CPG=240,
// RADIUS=1.2, SIGMA=0.9.
namespace {
constexpr int H_N     = 32;
constexpr int C_F     = 128;
constexpr int K_P     = 15;
constexpr int MODC    = 240;
constexpr int NSLICE  = 64;               // compaction slices (spread atomics)
constexpr int TILE_SZ = 64 * MODC * 2;    // 30720: x/h swz [0,16K), then mod
}

typedef __attribute__((ext_vector_type(8))) short short8v;
typedef __attribute__((ext_vector_type(4))) float f32x4;

__device__ __forceinline__ unsigned short bf16_hi(float f) {
    unsigned u = __builtin_bit_cast(unsigned, f);
    unsigned r = (u + 0x7FFFu + ((u >> 16) & 1u)) >> 16;
    return (unsigned short)r;
}
__device__ __forceinline__ float bf16_f(unsigned short h) {
    unsigned u = ((unsigned)h) << 16;
    return __builtin_bit_cast(float, u);
}

// ---------------------------------------------------------------------------
// Pre-pass: transpose weights to bf16 [col][k]; zero the 64 slice counters
// (padded 16 dwords apart -> no shared cache line between counters).
// ---------------------------------------------------------------------------
__global__ __launch_bounds__(256)
void split_w_kernel(const float* __restrict__ w1, const float* __restrict__ w2,
                    unsigned short* __restrict__ w1t, unsigned short* __restrict__ w2t,
                    int* __restrict__ cnt)
{
    const int i = blockIdx.x * 256 + threadIdx.x;
    if (i < NSLICE) cnt[i * 16] = 0;
    if (i < C_F * C_F) {
        const int c = i >> 7, j = i & 127;          // w1[c][j]
        w1t[j * C_F + c] = bf16_hi(w1[i]);
    }
    const int i2 = i - C_F * C_F;
    if (i2 >= 0 && i2 < C_F * MODC) {
        const int c = i2 / MODC, j = i2 - c * MODC; // w2[c][j]
        w2t[j * C_F + c] = bf16_hi(w2[i2]);
    }
}

// ---------------------------------------------------------------------------
// Geometry: round-2's PROVEN high-TLP shape (1 wave/query, 4 waves/block,
// 12.5k blocks, zero LDS -> ~1.5us for all 1.6M pairs in round 2).
// Inactive queries (~94%) -> out=0 immediately. Active -> append records to
// slice (blockIdx & 63): 64 spread counters avoid round-14's single-address
// atomic drain. Slot order is timing-dependent, but per-query VALUES are
// slot-independent -> output bitwise deterministic.
// ---------------------------------------------------------------------------
__global__ __launch_bounds__(256)
void geom_kernel(const float* __restrict__ q_pts,
                 const float* __restrict__ s_pts,
                 const int* __restrict__ nbi,
                 const float* __restrict__ da_scale,
                 const float* __restrict__ kp,
                 int* __restrict__ cnt,         // [NSLICE*16], padded
                 int* __restrict__ qidx,        // [NSLICE * cap]
                 unsigned* __restrict__ pk,     // [NSLICE * cap * 32]
                 float* __restrict__ gfl,       // [NSLICE * cap * 32]
                 float* __restrict__ out,
                 int M, int cap)
{
    const int t    = threadIdx.x;
    const int lane = t & 63;
    const int q    = blockIdx.x * 4 + (t >> 6);
    if (q >= M) return;

    int   idx = 0, nn = 0;
    float fl  = 0.f;
    if (lane < H_N) {
        const float qx = q_pts[q * 3 + 0];
        const float qy = q_pts[q * 3 + 1];
        const float qz = q_pts[q * 3 + 2];
        const float das = da_scale[q];
        idx = nbi[(size_t)q * H_N + lane];
        const float sx = s_pts[idx * 3 + 0];
        const float sy = s_pts[idx * 3 + 1];
        const float sz = s_pts[idx * 3 + 2];
        // plain fp32 (no fma contraction) to match numpy rounding at argmin ties
        const float dx = __fsub_rn(sx, qx);
        const float dy = __fsub_rn(sy, qy);
        const float dz = __fsub_rn(sz, qz);
        const float dd = __fadd_rn(__fadd_rn(__fmul_rn(dx, dx), __fmul_rn(dy, dy)),
                                   __fmul_rn(dz, dz));
        // |kp| < 1.2 strictly => |d| >= 0.9 + 1.2*da implies infl == 0 exactly.
        const float reach = 0.9f + 1.2f * das;
        if (dd < reach * reach) {
            float best = 3.4e38f; int bi = 0;
            #pragma unroll
            for (int k = 0; k < K_P; ++k) {
                const float ex = __fsub_rn(dx, __fmul_rn(kp[k * 3 + 0], das));
                const float ey = __fsub_rn(dy, __fmul_rn(kp[k * 3 + 1], das));
                const float ez = __fsub_rn(dz, __fmul_rn(kp[k * 3 + 2], das));
                const float d2 = __fadd_rn(__fadd_rn(__fmul_rn(ex, ex), __fmul_rn(ey, ey)),
                                           __fmul_rn(ez, ez));
                if (d2 < best) { best = d2; bi = k; }
            }
            const float f = 1.f - sqrtf(best) / 0.9f;
            fl = fmaxf(f, 0.f);
            nn = bi;
        }
    }

    const unsigned long long mask = __ballot(fl > 0.f);
    if (mask == 0ull) {
        // inactive: output row is exactly zero (64 lanes x float2 = 512B)
        reinterpret_cast<float2*>(out + (size_t)q * C_F)[lane] = make_float2(0.f, 0.f);
        return;
    }
    const int s = blockIdx.x & (NSLICE - 1);
    int slot = 0;
    if (lane == 0) slot = atomicAdd(&cnt[s * 16], 1);
    slot = __shfl(slot, 0);
    const size_t base = (size_t)s * cap + slot;
    if (lane == 0) qidx[base] = q;
    if (lane < H_N) {
        pk [base * H_N + lane] = (unsigned)idx | ((unsigned)nn << 20);
        gfl[base * H_N + lane] = fl;
    }
}

// ---------------------------------------------------------------------------
// MLP + gather over compacted rows. Grid (tiles, NSLICE); block (bx, s)
// handles rows bx*64.. of slice s. ~94% of blocks exit on cnt; ~60 live
// blocks of <=64 rows each run the round-16 MFMA MLP + gather tail.
// ---------------------------------------------------------------------------
__global__ __launch_bounds__(512, 2)
void active_kernel(const float* __restrict__ s_feats,
                   const float* __restrict__ weights,
                   const unsigned short* __restrict__ w1t,
                   const unsigned short* __restrict__ w2t,
                   const float* __restrict__ b1,
                   const int* __restrict__ cnt,
                   const int* __restrict__ qidx,
                   const unsigned* __restrict__ pk,
                   const float* __restrict__ gfl,
                   float* __restrict__ out, int cap)
{
    __shared__ __align__(16) unsigned char tile[TILE_SZ];

    const int s = blockIdx.y;
    const int rows = min(cnt[s * 16] - (int)blockIdx.x * 64, 64);
    if (rows <= 0) return;
    const size_t base = (size_t)s * cap + blockIdx.x * 64;

    const int t = threadIdx.x;
    const int wave = t >> 6, lane = t & 63;
    const int g  = lane >> 4;      // k-block
    const int ln = lane & 15;
    const int hl   = lane & 31;
    const int half = lane >> 5;

    // ---- prefetch weight fragments into registers ----
    short8v w1f[4];
    #pragma unroll
    for (int ks = 0; ks < 4; ++ks)
        w1f[ks] = *reinterpret_cast<const short8v*>(
            w1t + (size_t)(wave * 16 + ln) * C_F + ks * 32 + g * 8);
    short8v w2f[4][2];
    #pragma unroll
    for (int ks = 0; ks < 4; ++ks) {
        #pragma unroll
        for (int cs = 0; cs < 2; ++cs) {
            const int ctile = wave + 8 * cs;
            const int colc = (ctile < K_P ? ctile : 0) * 16 + ln;   // clamp: safe load
            w2f[ks][cs] = *reinterpret_cast<const short8v*>(
                w2t + (size_t)colc * C_F + ks * 32 + g * 8);
        }
    }

    // ---- stage x (gathered rows): fp32 -> bf16, swizzled LDS [row][k] ----
    {
        const int row = t >> 3;          // 0..63
        const int k0  = (t & 7) << 4;    // 0,16,...,112
        const int src_m = (row < rows) ? qidx[base + row] : 0;
        const float4* src = reinterpret_cast<const float4*>(
            s_feats + (size_t)src_m * C_F + k0);
        #pragma unroll
        for (int sp = 0; sp < 2; ++sp) {
            float v[8];
            if (row < rows) {
                const float4 a = src[sp * 2 + 0];
                const float4 b = src[sp * 2 + 1];
                v[0] = a.x; v[1] = a.y; v[2] = a.z; v[3] = a.w;
                v[4] = b.x; v[5] = b.y; v[6] = b.z; v[7] = b.w;
            } else {
                #pragma unroll
                for (int e = 0; e < 8; ++e) v[e] = 0.f;
            }
            short8v hv;
            #pragma unroll
            for (int e = 0; e < 8; ++e) hv[e] = (short)bf16_hi(v[e]);
            const unsigned addr = (unsigned)((row * 256 + (k0 + sp * 8) * 2) ^ ((row & 7) << 4));
            *reinterpret_cast<short8v*>(tile + addr) = hv;
        }
    }
    __syncthreads();

    // ---- GEMM1: h = leaky_relu(x @ w1 + b1); wave owns col-tile `wave` ----
    {
        const int col = wave * 16 + ln;
        f32x4 acc[4];
        {
            const float b = b1[col];
            #pragma unroll
            for (int rt = 0; rt < 4; ++rt) acc[rt] = f32x4{b, b, b, b};
        }
        #pragma unroll
        for (int ks = 0; ks < 4; ++ks) {
            short8v a[4];
            #pragma unroll
            for (int rt = 0; rt < 4; ++rt) {
                const int row = rt * 16 + ln;
                const unsigned addr = (unsigned)((row * 256 + (ks * 32 + g * 8) * 2) ^ ((row & 7) << 4));
                a[rt] = *reinterpret_cast<const short8v*>(tile + addr);
            }
            #pragma unroll
            for (int rt = 0; rt < 4; ++rt)
                acc[rt] = __builtin_amdgcn_mfma_f32_16x16x32_bf16(a[rt], w1f[ks], acc[rt], 0, 0, 0);
        }
        __syncthreads();   // all waves done reading x before h overwrites it

        // leaky_relu + writeback (C/D: col=ln, row=g*4+r)
        #pragma unroll
        for (int rt = 0; rt < 4; ++rt) {
            #pragma unroll
            for (int r = 0; r < 4; ++r) {
                float v = acc[rt][r];
                v = v > 0.f ? v : 0.1f * v;
                const int row = rt * 16 + g * 4 + r;
                const unsigned addr = (unsigned)((row * 256 + col * 2) ^ ((row & 7) << 4));
                *reinterpret_cast<unsigned short*>(tile + addr) = bf16_hi(v);
            }
        }
    }
    __syncthreads();

    // ---- GEMM2: mod = sigmoid(h @ w2) in registers; wave owns {w, w+8} ----
    f32x4 acc2[4][2];
    #pragma unroll
    for (int rt = 0; rt < 4; ++rt)
        #pragma unroll
        for (int cs = 0; cs < 2; ++cs) acc2[rt][cs] = f32x4{0.f, 0.f, 0.f, 0.f};

    #pragma unroll
    for (int ks = 0; ks < 4; ++ks) {
        short8v a[4];
        #pragma unroll
        for (int rt = 0; rt < 4; ++rt) {
            const int row = rt * 16 + ln;
            const unsigned addr = (unsigned)((row * 256 + (ks * 32 + g * 8) * 2) ^ ((row & 7) << 4));
            a[rt] = *reinterpret_cast<const short8v*>(tile + addr);
        }
        #pragma unroll
        for (int cs = 0; cs < 2; ++cs) {
            const int ctile = wave + 8 * cs;    // wave-uniform guard, static acc idx
            if (ctile < K_P) {
                #pragma unroll
                for (int rt = 0; rt < 4; ++rt)
                    acc2[rt][cs] = __builtin_amdgcn_mfma_f32_16x16x32_bf16(a[rt], w2f[ks][cs], acc2[rt][cs], 0, 0, 0);
            }
        }
    }
    #pragma unroll
    for (int rt = 0; rt < 4; ++rt)
        #pragma unroll
        for (int cs = 0; cs < 2; ++cs)
            #pragma unroll
            for (int r = 0; r < 4; ++r)
                acc2[rt][cs][r] = 1.f / (1.f + __expf(-acc2[rt][cs][r]));

    __syncthreads();   // h reads complete -> mod may overwrite the tile

    // ---- mod -> LDS (linear bf16 [64][240]) ----
    #pragma unroll
    for (int rt = 0; rt < 4; ++rt) {
        #pragma unroll
        for (int cs = 0; cs < 2; ++cs) {
            const int ctile = wave + 8 * cs;
            if (ctile < K_P) {
                const int col = ctile * 16 + ln;
                #pragma unroll
                for (int r = 0; r < 4; ++r) {
                    const int row = rt * 16 + g * 4 + r;
                    *reinterpret_cast<unsigned short*>(
                        tile + row * (MODC * 2) + col * 2) = bf16_hi(acc2[rt][cs][r]);
                }
            }
        }
    }
    __syncthreads();

    // ---- gather tail: records from global (L2-hot), mod from LDS ----
    const int c0 = hl << 2;          // 4 channels per lane
    for (int i = 0; i < 4; ++i) {
        const int pos = i * 16 + wave * 2 + half;
        const bool valid = pos < rows;

        int   idx = 0, nn = 0;
        float fl  = 0.f;
        if (valid) {
            const unsigned r = pk[(base + pos) * H_N + hl];
            idx = (int)(r & 0xFFFFFu);
            nn  = (int)(r >> 20);
            fl  = gfl[(base + pos) * H_N + hl];
        }

        const unsigned long long mask = __ballot(fl > 0.f);
        unsigned long long mymask = half ? (mask & 0xFFFFFFFF00000000ull)
                                         : (mask & 0x00000000FFFFFFFFull);
        float4 acc = {0.f, 0.f, 0.f, 0.f};
        while (mymask) {
            const int hb = __builtin_ctzll(mymask);   // absolute lane (correct half)
            mymask &= mymask - 1;
            const int   ih = __shfl(idx, hb);
            const int   nh = __shfl(nn, hb);
            const float fh = __shfl(fl, hb);
            const float4 fv = *reinterpret_cast<const float4*>(s_feats + (size_t)ih * C_F + c0);
            const float4 wv = *reinterpret_cast<const float4*>(weights + nh * C_F + c0);
            const float  mv = bf16_f(*reinterpret_cast<const unsigned short*>(
                tile + pos * (MODC * 2) + (nh * 16 + (hl >> 1)) * 2));
            const float  s2 = fh * mv;
            acc.x = fmaf(fv.x * wv.x, s2, acc.x);
            acc.y = fmaf(fv.y * wv.y, s2, acc.y);
            acc.z = fmaf(fv.z * wv.z, s2, acc.z);
            acc.w = fmaf(fv.w * wv.w, s2, acc.w);
        }
        if (valid)
            *reinterpret_cast<float4*>(out + (size_t)qidx[base + pos] * C_F + c0) = acc;
    }
}

// ---------------------------------------------------------------------------
extern "C" void kernel_launch(void* const* d_in, const int* in_sizes, int n_in,
                              void* d_out, int out_size, void* d_ws, size_t ws_size,
                              hipStream_t stream)
{
    const float* q_pts  = (const float*)d_in[0];
    const float* s_pts  = (const float*)d_in[1];
    const float* s_feat = (const float*)d_in[2];
    const int*   nbi    = (const int*)d_in[3];
    const float* da     = (const float*)d_in[4];
    const float* wts    = (const float*)d_in[5];
    const float* w1     = (const float*)d_in[6];
    const float* b1     = (const float*)d_in[7];
    const float* w2     = (const float*)d_in[8];
    const float* kp     = (const float*)d_in[9];
    float* out = (float*)d_out;

    const int M = in_sizes[4];   // da_scale has M elements

    // slice capacity: worst case all queries active in one slice's blocks
    const int nbg  = (M + 3) / 4;                 // geom blocks (4 queries each)
    const int maxb = (nbg + NSLICE - 1) / NSLICE; // geom blocks per slice
    const int cap  = maxb * 4;                    // rows per slice region
    const int ntile = (cap + 63) / 64;            // active tiles per slice

    // ws: w1t 32KB | w2t 60KB | cnt[64*16] | qidx[64*cap] | pk | gfl
    unsigned short* w1t = (unsigned short*)d_ws;
    unsigned short* w2t = w1t + C_F * C_F;
    size_t off = ((size_t)(C_F * C_F + C_F * MODC) * sizeof(unsigned short) + 255) & ~(size_t)255;
    int* cnt  = (int*)((char*)d_ws + off);            off += NSLICE * 16 * 4;
    int* qidx = (int*)((char*)d_ws + off);            off += (size_t)NSLICE * cap * 4;
    off = (off + 255) & ~(size_t)255;
    unsigned* pk = (unsigned*)((char*)d_ws + off);    off += (size_t)NSLICE * cap * H_N * 4;
    float* gfl   = (float*)((char*)d_ws + off);

    const int nsplit = (C_F * C_F + C_F * MODC + 255) / 256;
    split_w_kernel<<<dim3(nsplit), 256, 0, stream>>>(w1, w2, w1t, w2t, cnt);

    geom_kernel<<<dim3(nbg), 256, 0, stream>>>(
        q_pts, s_pts, nbi, da, kp, cnt, qidx, pk, gfl, out, M, cap);

    active_kernel<<<dim3(ntile, NSLICE), 512, 0, stream>>>(
        s_feat, wts, w1t, w2t, b1, cnt, qidx, pk, gfl, out, cap);
}

// Round 19
// 40.818 us; speedup vs baseline: 1.0939x; 1.0397x over previous
//
#include <hip/hip_runtime.h>
#include <cstddef>
#include <cstdint>

// KPNextBlock: M=N=50000, H=32, C=128, K=15, GROUPS=8, CPG=16 -> K*CPG=240,
// RADIUS=1.2, SIGMA=0.9.
namespace {
constexpr int H_N     = 32;
constexpr int C_F     = 128;
constexpr int K_P     = 15;
constexpr int MODC    = 240;
constexpr int NSLICE  = 64;               // compaction slices (spread atomics)
constexpr int TILE_SZ = 64 * MODC * 2;    // 30720: x/h swz [0,16K), then mod
}

typedef __attribute__((ext_vector_type(8))) short short8v;
typedef __attribute__((ext_vector_type(4))) float f32x4;

__device__ __forceinline__ unsigned short bf16_hi(float f) {
    unsigned u = __builtin_bit_cast(unsigned, f);
    unsigned r = (u + 0x7FFFu + ((u >> 16) & 1u)) >> 16;
    return (unsigned short)r;
}
__device__ __forceinline__ float bf16_f(unsigned short h) {
    unsigned u = ((unsigned)h) << 16;
    return __builtin_bit_cast(float, u);
}

// ---------------------------------------------------------------------------
// Pre-pass: transpose weights to bf16 [col][k]; zero the 64 slice counters.
// ---------------------------------------------------------------------------
__global__ __launch_bounds__(256)
void split_w_kernel(const float* __restrict__ w1, const float* __restrict__ w2,
                    unsigned short* __restrict__ w1t, unsigned short* __restrict__ w2t,
                    int* __restrict__ cnt)
{
    const int i = blockIdx.x * 256 + threadIdx.x;
    if (i < NSLICE) cnt[i * 16] = 0;
    if (i < C_F * C_F) {
        const int c = i >> 7, j = i & 127;          // w1[c][j]
        w1t[j * C_F + c] = bf16_hi(w1[i]);
    }
    const int i2 = i - C_F * C_F;
    if (i2 >= 0 && i2 < C_F * MODC) {
        const int c = i2 / MODC, j = i2 - c * MODC; // w2[c][j]
        w2t[j * C_F + c] = bf16_hi(w2[i2]);
    }
}

// ---------------------------------------------------------------------------
// Geometry: 2 queries/wave (half-wave each, ALL 64 lanes active), 4 waves per
// 256-thread block, 6250 blocks, zero LDS, kp PRELOADED into registers
// (round-14's VGPR=12 proved the 45 kp loads re-issued per argmin loop as a
// dependent L1 chain). Inactive queries write NOTHING (out pre-zeroed by
// hipMemsetAsync at HBM fill rate instead of scattered 512B stores).
// Active -> records appended to slice (blockIdx & 63), 64 spread counters.
// ---------------------------------------------------------------------------
__global__ __launch_bounds__(256, 2)
void geom_kernel(const float* __restrict__ q_pts,
                 const float* __restrict__ s_pts,
                 const int* __restrict__ nbi,
                 const float* __restrict__ da_scale,
                 const float* __restrict__ kp,
                 int* __restrict__ cnt,         // [NSLICE*16], padded
                 int* __restrict__ qidx,        // [NSLICE * cap]
                 unsigned* __restrict__ pk,     // [NSLICE * cap * 32]
                 float* __restrict__ gfl,       // [NSLICE * cap * 32]
                 int M, int cap)
{
    const int t    = threadIdx.x;
    const int lane = t & 63;
    const int hl   = lane & 31;      // neighbor index within the query
    const int half = lane >> 5;
    const int q    = blockIdx.x * 8 + (t >> 6) * 2 + half;
    const bool valid = q < M;

    // ---- preload kernel points into registers (once, uniform) ----
    float kpx[K_P], kpy[K_P], kpz[K_P];
    #pragma unroll
    for (int k = 0; k < K_P; ++k) {
        kpx[k] = kp[k * 3 + 0];
        kpy[k] = kp[k * 3 + 1];
        kpz[k] = kp[k * 3 + 2];
    }

    int   idx = 0, nn = 0;
    float fl  = 0.f;
    if (valid) {
        const float qx = q_pts[q * 3 + 0];
        const float qy = q_pts[q * 3 + 1];
        const float qz = q_pts[q * 3 + 2];
        const float das = da_scale[q];
        idx = nbi[(size_t)q * H_N + hl];
        const float sx = s_pts[idx * 3 + 0];
        const float sy = s_pts[idx * 3 + 1];
        const float sz = s_pts[idx * 3 + 2];
        // plain fp32 (no fma contraction) to match numpy rounding at argmin ties
        const float dx = __fsub_rn(sx, qx);
        const float dy = __fsub_rn(sy, qy);
        const float dz = __fsub_rn(sz, qz);
        const float dd = __fadd_rn(__fadd_rn(__fmul_rn(dx, dx), __fmul_rn(dy, dy)),
                                   __fmul_rn(dz, dz));
        // |kp| < 1.2 strictly => |d| >= 0.9 + 1.2*da implies infl == 0 exactly.
        const float reach = 0.9f + 1.2f * das;
        if (dd < reach * reach) {
            float best = 3.4e38f; int bi = 0;
            #pragma unroll
            for (int k = 0; k < K_P; ++k) {
                const float ex = __fsub_rn(dx, __fmul_rn(kpx[k], das));
                const float ey = __fsub_rn(dy, __fmul_rn(kpy[k], das));
                const float ez = __fsub_rn(dz, __fmul_rn(kpz[k], das));
                const float d2 = __fadd_rn(__fadd_rn(__fmul_rn(ex, ex), __fmul_rn(ey, ey)),
                                           __fmul_rn(ez, ez));
                if (d2 < best) { best = d2; bi = k; }
            }
            const float f = 1.f - sqrtf(best) / 0.9f;
            fl = fmaxf(f, 0.f);
            nn = bi;
        }
    }

    const unsigned long long mask = __ballot(fl > 0.f);
    const unsigned long long mymask = half ? (mask & 0xFFFFFFFF00000000ull)
                                           : (mask & 0x00000000FFFFFFFFull);
    if (!valid || mymask == 0ull) return;   // inactive: out already zeroed

    const int s = blockIdx.x & (NSLICE - 1);
    int slot = 0;
    if (hl == 0) slot = atomicAdd(&cnt[s * 16], 1);
    slot = __shfl(slot, half * 32);
    const size_t base = (size_t)s * cap + slot;
    if (hl == 0) qidx[base] = q;
    pk [base * H_N + hl] = (unsigned)idx | ((unsigned)nn << 20);
    gfl[base * H_N + hl] = fl;
}

// ---------------------------------------------------------------------------
// MLP + gather over compacted rows. Grid (tiles, NSLICE); ~94% of blocks exit
// on cnt; live blocks run the MFMA MLP + gather tail (round-16 structure).
// ---------------------------------------------------------------------------
__global__ __launch_bounds__(512, 2)
void active_kernel(const float* __restrict__ s_feats,
                   const float* __restrict__ weights,
                   const unsigned short* __restrict__ w1t,
                   const unsigned short* __restrict__ w2t,
                   const float* __restrict__ b1,
                   const int* __restrict__ cnt,
                   const int* __restrict__ qidx,
                   const unsigned* __restrict__ pk,
                   const float* __restrict__ gfl,
                   float* __restrict__ out, int cap)
{
    __shared__ __align__(16) unsigned char tile[TILE_SZ];

    const int s = blockIdx.y;
    const int rows = min(cnt[s * 16] - (int)blockIdx.x * 64, 64);
    if (rows <= 0) return;
    const size_t base = (size_t)s * cap + blockIdx.x * 64;

    const int t = threadIdx.x;
    const int wave = t >> 6, lane = t & 63;
    const int g  = lane >> 4;      // k-block
    const int ln = lane & 15;
    const int hl   = lane & 31;
    const int half = lane >> 5;

    // ---- prefetch weight fragments into registers ----
    short8v w1f[4];
    #pragma unroll
    for (int ks = 0; ks < 4; ++ks)
        w1f[ks] = *reinterpret_cast<const short8v*>(
            w1t + (size_t)(wave * 16 + ln) * C_F + ks * 32 + g * 8);
    short8v w2f[4][2];
    #pragma unroll
    for (int ks = 0; ks < 4; ++ks) {
        #pragma unroll
        for (int cs = 0; cs < 2; ++cs) {
            const int ctile = wave + 8 * cs;
            const int colc = (ctile < K_P ? ctile : 0) * 16 + ln;   // clamp: safe load
            w2f[ks][cs] = *reinterpret_cast<const short8v*>(
                w2t + (size_t)colc * C_F + ks * 32 + g * 8);
        }
    }

    // ---- stage x (gathered rows): fp32 -> bf16, swizzled LDS [row][k] ----
    {
        const int row = t >> 3;          // 0..63
        const int k0  = (t & 7) << 4;    // 0,16,...,112
        const int src_m = (row < rows) ? qidx[base + row] : 0;
        const float4* src = reinterpret_cast<const float4*>(
            s_feats + (size_t)src_m * C_F + k0);
        #pragma unroll
        for (int sp = 0; sp < 2; ++sp) {
            float v[8];
            if (row < rows) {
                const float4 a = src[sp * 2 + 0];
                const float4 b = src[sp * 2 + 1];
                v[0] = a.x; v[1] = a.y; v[2] = a.z; v[3] = a.w;
                v[4] = b.x; v[5] = b.y; v[6] = b.z; v[7] = b.w;
            } else {
                #pragma unroll
                for (int e = 0; e < 8; ++e) v[e] = 0.f;
            }
            short8v hv;
            #pragma unroll
            for (int e = 0; e < 8; ++e) hv[e] = (short)bf16_hi(v[e]);
            const unsigned addr = (unsigned)((row * 256 + (k0 + sp * 8) * 2) ^ ((row & 7) << 4));
            *reinterpret_cast<short8v*>(tile + addr) = hv;
        }
    }
    __syncthreads();

    // ---- GEMM1: h = leaky_relu(x @ w1 + b1); wave owns col-tile `wave` ----
    {
        const int col = wave * 16 + ln;
        f32x4 acc[4];
        {
            const float b = b1[col];
            #pragma unroll
            for (int rt = 0; rt < 4; ++rt) acc[rt] = f32x4{b, b, b, b};
        }
        #pragma unroll
        for (int ks = 0; ks < 4; ++ks) {
            short8v a[4];
            #pragma unroll
            for (int rt = 0; rt < 4; ++rt) {
                const int row = rt * 16 + ln;
                const unsigned addr = (unsigned)((row * 256 + (ks * 32 + g * 8) * 2) ^ ((row & 7) << 4));
                a[rt] = *reinterpret_cast<const short8v*>(tile + addr);
            }
            #pragma unroll
            for (int rt = 0; rt < 4; ++rt)
                acc[rt] = __builtin_amdgcn_mfma_f32_16x16x32_bf16(a[rt], w1f[ks], acc[rt], 0, 0, 0);
        }
        __syncthreads();   // all waves done reading x before h overwrites it

        // leaky_relu + writeback (C/D: col=ln, row=g*4+r)
        #pragma unroll
        for (int rt = 0; rt < 4; ++rt) {
            #pragma unroll
            for (int r = 0; r < 4; ++r) {
                float v = acc[rt][r];
                v = v > 0.f ? v : 0.1f * v;
                const int row = rt * 16 + g * 4 + r;
                const unsigned addr = (unsigned)((row * 256 + col * 2) ^ ((row & 7) << 4));
                *reinterpret_cast<unsigned short*>(tile + addr) = bf16_hi(v);
            }
        }
    }
    __syncthreads();

    // ---- GEMM2: mod = sigmoid(h @ w2) in registers; wave owns {w, w+8} ----
    f32x4 acc2[4][2];
    #pragma unroll
    for (int rt = 0; rt < 4; ++rt)
        #pragma unroll
        for (int cs = 0; cs < 2; ++cs) acc2[rt][cs] = f32x4{0.f, 0.f, 0.f, 0.f};

    #pragma unroll
    for (int ks = 0; ks < 4; ++ks) {
        short8v a[4];
        #pragma unroll
        for (int rt = 0; rt < 4; ++rt) {
            const int row = rt * 16 + ln;
            const unsigned addr = (unsigned)((row * 256 + (ks * 32 + g * 8) * 2) ^ ((row & 7) << 4));
            a[rt] = *reinterpret_cast<const short8v*>(tile + addr);
        }
        #pragma unroll
        for (int cs = 0; cs < 2; ++cs) {
            const int ctile = wave + 8 * cs;    // wave-uniform guard, static acc idx
            if (ctile < K_P) {
                #pragma unroll
                for (int rt = 0; rt < 4; ++rt)
                    acc2[rt][cs] = __builtin_amdgcn_mfma_f32_16x16x32_bf16(a[rt], w2f[ks][cs], acc2[rt][cs], 0, 0, 0);
            }
        }
    }
    #pragma unroll
    for (int rt = 0; rt < 4; ++rt)
        #pragma unroll
        for (int cs = 0; cs < 2; ++cs)
            #pragma unroll
            for (int r = 0; r < 4; ++r)
                acc2[rt][cs][r] = 1.f / (1.f + __expf(-acc2[rt][cs][r]));

    __syncthreads();   // h reads complete -> mod may overwrite the tile

    // ---- mod -> LDS (linear bf16 [64][240]) ----
    #pragma unroll
    for (int rt = 0; rt < 4; ++rt) {
        #pragma unroll
        for (int cs = 0; cs < 2; ++cs) {
            const int ctile = wave + 8 * cs;
            if (ctile < K_P) {
                const int col = ctile * 16 + ln;
                #pragma unroll
                for (int r = 0; r < 4; ++r) {
                    const int row = rt * 16 + g * 4 + r;
                    *reinterpret_cast<unsigned short*>(
                        tile + row * (MODC * 2) + col * 2) = bf16_hi(acc2[rt][cs][r]);
                }
            }
        }
    }
    __syncthreads();

    // ---- gather tail: records from global (L2-hot), mod from LDS ----
    const int c0 = hl << 2;          // 4 channels per lane
    for (int i = 0; i < 4; ++i) {
        const int pos = i * 16 + wave * 2 + half;
        const bool valid = pos < rows;

        int   idx = 0, nn = 0;
        float fl  = 0.f;
        if (valid) {
            const unsigned r = pk[(base + pos) * H_N + hl];
            idx = (int)(r & 0xFFFFFu);
            nn  = (int)(r >> 20);
            fl  = gfl[(base + pos) * H_N + hl];
        }

        const unsigned long long mask = __ballot(fl > 0.f);
        unsigned long long mymask = half ? (mask & 0xFFFFFFFF00000000ull)
                                         : (mask & 0x00000000FFFFFFFFull);
        float4 acc = {0.f, 0.f, 0.f, 0.f};
        while (mymask) {
            const int hb = __builtin_ctzll(mymask);   // absolute lane (correct half)
            mymask &= mymask - 1;
            const int   ih = __shfl(idx, hb);
            const int   nh = __shfl(nn, hb);
            const float fh = __shfl(fl, hb);
            const float4 fv = *reinterpret_cast<const float4*>(s_feats + (size_t)ih * C_F + c0);
            const float4 wv = *reinterpret_cast<const float4*>(weights + nh * C_F + c0);
            const float  mv = bf16_f(*reinterpret_cast<const unsigned short*>(
                tile + pos * (MODC * 2) + (nh * 16 + (hl >> 1)) * 2));
            const float  s2 = fh * mv;
            acc.x = fmaf(fv.x * wv.x, s2, acc.x);
            acc.y = fmaf(fv.y * wv.y, s2, acc.y);
            acc.z = fmaf(fv.z * wv.z, s2, acc.z);
            acc.w = fmaf(fv.w * wv.w, s2, acc.w);
        }
        if (valid)
            *reinterpret_cast<float4*>(out + (size_t)qidx[base + pos] * C_F + c0) = acc;
    }
}

// ---------------------------------------------------------------------------
extern "C" void kernel_launch(void* const* d_in, const int* in_sizes, int n_in,
                              void* d_out, int out_size, void* d_ws, size_t ws_size,
                              hipStream_t stream)
{
    const float* q_pts  = (const float*)d_in[0];
    const float* s_pts  = (const float*)d_in[1];
    const float* s_feat = (const float*)d_in[2];
    const int*   nbi    = (const int*)d_in[3];
    const float* da     = (const float*)d_in[4];
    const float* wts    = (const float*)d_in[5];
    const float* w1     = (const float*)d_in[6];
    const float* b1     = (const float*)d_in[7];
    const float* w2     = (const float*)d_in[8];
    const float* kp     = (const float*)d_in[9];
    float* out = (float*)d_out;

    const int M = in_sizes[4];   // da_scale has M elements

    // zero the whole output at HBM fill rate; inactive rows stay zero,
    // active rows are fully overwritten by active_kernel.
    hipMemsetAsync(out, 0, (size_t)out_size * sizeof(float), stream);

    // slice capacity: worst case all 8 queries of every block in a slice active
    const int nbg   = (M + 7) / 8;                 // geom blocks (8 queries each)
    const int maxb  = (nbg + NSLICE - 1) / NSLICE; // geom blocks per slice
    const int cap   = maxb * 8;                    // rows per slice region
    const int ntile = (cap + 63) / 64;             // active tiles per slice

    // ws: w1t 32KB | w2t 60KB | cnt[64*16] | qidx[64*cap] | pk | gfl
    unsigned short* w1t = (unsigned short*)d_ws;
    unsigned short* w2t = w1t + C_F * C_F;
    size_t off = ((size_t)(C_F * C_F + C_F * MODC) * sizeof(unsigned short) + 255) & ~(size_t)255;
    int* cnt  = (int*)((char*)d_ws + off);            off += NSLICE * 16 * 4;
    int* qidx = (int*)((char*)d_ws + off);            off += (size_t)NSLICE * cap * 4;
    off = (off + 255) & ~(size_t)255;
    unsigned* pk = (unsigned*)((char*)d_ws + off);    off += (size_t)NSLICE * cap * H_N * 4;
    float* gfl   = (float*)((char*)d_ws + off);

    const int nsplit = (C_F * C_F + C_F * MODC + 255) / 256;
    split_w_kernel<<<dim3(nsplit), 256, 0, stream>>>(w1, w2, w1t, w2t, cnt);

    geom_kernel<<<dim3(nbg), 256, 0, stream>>>(
        q_pts, s_pts, nbi, da, kp, cnt, qidx, pk, gfl, M, cap);

    active_kernel<<<dim3(ntile, NSLICE), 512, 0, stream>>>(
        s_feat, wts, w1t, w2t, b1, cnt, qidx, pk, gfl, out, cap);
}